// Round 7
// baseline (499.160 us; speedup 1.0000x reference)
//
#include <hip/hip_runtime.h>

#define BB   128
#define DD   128
#define OUTN 100000
#define KP1  4097          // K+1
#define TEMP 0.07f

#define TJ   128           // j rows per tile
#define NT   782           // ceil(OUTN / TJ)
#define CAP  1536          // bucket capacity per tile (mean 671, +13 sigma safe)
#define SCORES (2 * BB * KP1)   // 1,048,832
#define NROW (OUTN * DD)   // 12,800,000 floats per memory
#define NSCALE_BLK 4097    // 4097*256 == SCORES exactly

// ws layout (float offsets): [0,128) Z buckets | [128,1024) cnt ints (782 used)
// | [1024, 1024+16384) z1t | buckets (uint) at 17408, NT*CAP entries (~4.8 MB;
// ws >= 102 MB proven in R4 by WRITE_SIZE=200MB => do_copy path ran)
#define WS_CNT_OFF 128
#define WS_Z1T_OFF 1024
#define WS_BKT_OFF 17408

typedef float vfloat4 __attribute__((ext_vector_type(4)));

// ---------------------------------------------------------------------------
// count_prep: blocks (0..16, b) bucket the (b,k) pairs by j-tile (atomic
// append, packed (jl<<20)|(b<<13)|k). Block (17, b) transposes z1 row b into
// z1t[d][b].
// ---------------------------------------------------------------------------
__global__ __launch_bounds__(256) void count_prep_kernel(
    const float* __restrict__ z1, const int* __restrict__ y,
    const int* __restrict__ idx, float* __restrict__ ws)
{
    const int b = blockIdx.y;
    if (blockIdx.x == 17) {
        float* z1t = ws + WS_Z1T_OFF;
        const int t = threadIdx.x;
        if (t < DD) z1t[t * BB + b] = z1[b * DD + t];
        return;
    }
    int* cnt = (int*)(ws + WS_CNT_OFF);
    unsigned* bkt = (unsigned*)(ws + WS_BKT_OFF);
    const int k = blockIdx.x * 256 + threadIdx.x;
    if (k >= KP1) return;
    const int j = (k == 0) ? y[b] : idx[b * KP1 + k];
    const int tile = j >> 7, jl = j & 127;
    const int pos = atomicAdd(&cnt[tile], 1);
    if (pos < CAP)
        bkt[tile * CAP + pos] =
            ((unsigned)jl << 20) | ((unsigned)b << 13) | (unsigned)k;
}

// ---------------------------------------------------------------------------
// gemm: per block, tile of 128 j x 128 b for both memories.
// d chunked by 32: abuf (mem tile slice, float4-over-d, XOR-swizzled) and
// zbuf (z1t slice, float4-over-b) both in LDS (16 KB each). Inner loop is
// pure LDS + FMA. Staging loads also stream the mem copy to out (nontemporal).
// Epilogue: park S half-tiles (64 j x 128 b = 32 KB) in LDS, walk this tile's
// inverted-index bucket, scatter exp(S/T) to score outputs, accumulate Z.
// ---------------------------------------------------------------------------
__global__ __launch_bounds__(256) void gemm_kernel(
    const float* __restrict__ mem2, const float* __restrict__ mem3,
    float* __restrict__ ws, float* __restrict__ out)
{
    __shared__ float lds[8192];                  // 32 KB
    vfloat4* abuf = (vfloat4*)lds;               // [128 j][8 c4]   16 KB
    vfloat4* zbuf = ((vfloat4*)lds) + 1024;      // [32 d][32 bq]   16 KB
                                                 // epilogue: lds = S half 32 KB
    const int t  = threadIdx.x;
    const int tx = t & 15;                       // b-quad: b=tx*4..+3, 64+...
    const int ty = t >> 4;                       // j-group: j=ty*8..+7
    const int tile = blockIdx.x;
    const long jt = (long)tile * TJ;

    const float* z1t = ws + WS_Z1T_OFF;
    const int*   cnt = (const int*)(ws + WS_CNT_OFF);
    const unsigned* bkt = (const unsigned*)(ws + WS_BKT_OFF);
    const int ncnt = min(cnt[tile], CAP);
    const vfloat4* zf = (const vfloat4*)z1t;

    float zacc2 = 0.f, zacc3 = 0.f;

    for (int m = 0; m < 2; ++m) {
        const vfloat4* mem = (const vfloat4*)(m ? mem3 : mem2);
        vfloat4* cd = (vfloat4*)(out + SCORES + (size_t)m * NROW);
        float* so = out + (size_t)m * BB * KP1;

        float acc[8][8];
        #pragma unroll
        for (int a = 0; a < 8; ++a)
            #pragma unroll
            for (int q = 0; q < 8; ++q) acc[a][q] = 0.f;

        for (int c = 0; c < 4; ++c) {
            __syncthreads();   // prior chunk's reads / prior m's epilogue done

            // ---- stage abuf (mem rows, 128B per row per chunk) + copy-out
            vfloat4 av[4]; int asl[4];
            #pragma unroll
            for (int i = 0; i < 4; ++i) {
                const int e = i * 256 + t;       // [0,1024)
                const int j = e >> 3, c4 = e & 7;
                const long gj = jt + j;
                vfloat4 v = {0.f, 0.f, 0.f, 0.f};
                if (gj < OUTN) {
                    v = mem[gj * 32 + c * 8 + c4];
                    __builtin_nontemporal_store(v, cd + gj * 32 + c * 8 + c4);
                }
                av[i] = v;
                asl[i] = j * 8 + ((c4 ^ (j >> 3)) & 7);   // XOR swizzle
            }
            // ---- stage zbuf (z1t slice, fully coalesced)
            #pragma unroll
            for (int i = 0; i < 4; ++i) {
                const int e = i * 256 + t;       // [0,1024)
                const int dd = e >> 5, bq = e & 31;
                zbuf[e] = zf[(c * 32 + dd) * 32 + bq];
            }
            #pragma unroll
            for (int i = 0; i < 4; ++i) abuf[asl[i]] = av[i];
            __syncthreads();

            // ---- compute: 8 d4-steps x 64 FMAs, pure LDS operands
            #pragma unroll
            for (int d4 = 0; d4 < 8; ++d4) {
                vfloat4 zA[4], zB[4];
                #pragma unroll
                for (int q = 0; q < 4; ++q) {
                    zA[q] = zbuf[(d4 * 4 + q) * 32 + tx];
                    zB[q] = zbuf[(d4 * 4 + q) * 32 + 16 + tx];
                }
                #pragma unroll
                for (int h = 0; h < 2; ++h) {
                    vfloat4 mj[4];
                    #pragma unroll
                    for (int r = 0; r < 4; ++r)
                        mj[r] = abuf[(ty * 8 + h * 4 + r) * 8 + ((d4 ^ ty) & 7)];
                    #pragma unroll
                    for (int q = 0; q < 4; ++q)
                        #pragma unroll
                        for (int r = 0; r < 4; ++r) {
                            const float mv = mj[r][q];
                            #pragma unroll
                            for (int i = 0; i < 4; ++i) {
                                acc[h * 4 + r][i]     += mv * zA[q][i];
                                acc[h * 4 + r][4 + i] += mv * zB[q][i];
                            }
                        }
                }
            }
        }

        // ---- epilogue: two 64-row S halves in LDS, scatter via bucket list
        #pragma unroll
        for (int h2 = 0; h2 < 2; ++h2) {
            __syncthreads();
            if ((ty >> 3) == h2) {
                vfloat4* Sh = (vfloat4*)lds;
                #pragma unroll
                for (int jj = 0; jj < 8; ++jj) {
                    const int jl2 = (ty & 7) * 8 + jj;   // 0..63
                    vfloat4 o0 = {acc[jj][0], acc[jj][1], acc[jj][2], acc[jj][3]};
                    vfloat4 o1 = {acc[jj][4], acc[jj][5], acc[jj][6], acc[jj][7]};
                    Sh[jl2 * 32 + tx]      = o0;
                    Sh[jl2 * 32 + 16 + tx] = o1;
                }
            }
            __syncthreads();
            for (int e = t; e < ncnt; e += 256) {
                const unsigned p = bkt[tile * CAP + e];
                const int jl = (int)(p >> 20);
                if ((jl >> 6) != h2) continue;
                const int eb = (int)((p >> 13) & 127);
                const int ek = (int)(p & 0x1FFF);
                const float s = expf(lds[(jl & 63) * 128 + eb] * (1.0f / TEMP));
                so[eb * KP1 + ek] = s;
                if (m) zacc3 += s; else zacc2 += s;
            }
        }
    }

    // ---- Z partial reduction -> 64 buckets
    #pragma unroll
    for (int off = 32; off > 0; off >>= 1) {
        zacc2 += __shfl_xor(zacc2, off);
        zacc3 += __shfl_xor(zacc3, off);
    }
    __shared__ float w2s[4], w3s[4];
    const int wave = t >> 6, lane = t & 63;
    if (lane == 0) { w2s[wave] = zacc2; w3s[wave] = zacc3; }
    __syncthreads();
    if (t == 0) {
        const int slot = tile & 63;
        atomicAdd(&ws[slot],      w2s[0] + w2s[1] + w2s[2] + w2s[3]);
        atomicAdd(&ws[64 + slot], w3s[0] + w3s[1] + w3s[2] + w3s[3]);
    }
}

// ---------------------------------------------------------------------------
// Finalize kernel, block zones (proven):
//   [0, 4097):    read 128 bucket sums (thread 0, L2-hot), scale scores
//   [4097, 4225): row update for b = blockIdx - 4097 (parallel dup check)
// ---------------------------------------------------------------------------
__global__ __launch_bounds__(256) void finalize_kernel(
    const float* __restrict__ z2,
    const float* __restrict__ z3,
    const float* __restrict__ mem2,
    const float* __restrict__ mem3,
    const int*   __restrict__ y,
    float* __restrict__ out,
    const float* __restrict__ part)
{
    const int t = threadIdx.x;

    if (blockIdx.x < NSCALE_BLK) {
        __shared__ float sc[2];
        if (t == 0) {
            float t2 = 0.f, t3 = 0.f;
            for (int i = 0; i < 64; ++i) { t2 += part[i]; t3 += part[64 + i]; }
            sc[0] = (float)((double)(BB * KP1) / ((double)OUTN * (double)t2));
            sc[1] = (float)((double)(BB * KP1) / ((double)OUTN * (double)t3));
        }
        __syncthreads();
        const int i = blockIdx.x * 256 + t;       // always < SCORES
        out[i] *= sc[(i < BB * KP1) ? 0 : 1];
        return;
    }

    // ---- update zone: pos = 2*z - mem[y] (momentum = -1), L2-normalize
    const int b  = blockIdx.x - NSCALE_BLK;
    const int yb = y[b];

    __shared__ int dup;
    if (t == 0) dup = 0;
    __syncthreads();
    if (t > b && t < BB && y[t] == yb) dup = 1;   // parallel duplicate scan
    __syncthreads();
    if (dup) return;                              // a later b' overwrites row
    if (t >= 64) return;

    float* out2 = out + SCORES;
    float* out3 = out2 + NROW;

    const float2 m2 = *(const float2*)(mem2 + (size_t)yb * DD + 2 * t);
    const float2 m3 = *(const float2*)(mem3 + (size_t)yb * DD + 2 * t);
    const float2 a2 = *(const float2*)(z2 + b * DD + 2 * t);
    const float2 a3 = *(const float2*)(z3 + b * DD + 2 * t);

    float2 p2, p3;
    p2.x = 2.f * a2.x - m2.x;  p2.y = 2.f * a2.y - m2.y;
    p3.x = 2.f * a3.x - m3.x;  p3.y = 2.f * a3.y - m3.y;

    float ss2 = p2.x * p2.x + p2.y * p2.y;
    float ss3 = p3.x * p3.x + p3.y * p3.y;
    #pragma unroll
    for (int off = 32; off > 0; off >>= 1) {
        ss2 += __shfl_xor(ss2, off);
        ss3 += __shfl_xor(ss3, off);
    }
    const float inv2 = 1.f / sqrtf(ss2);
    const float inv3 = 1.f / sqrtf(ss3);

    float2 w2, w3;
    w2.x = p2.x * inv2;  w2.y = p2.y * inv2;
    w3.x = p3.x * inv3;  w3.y = p3.y * inv3;
    *(float2*)(out2 + (size_t)yb * DD + 2 * t) = w2;
    *(float2*)(out3 + (size_t)yb * DD + 2 * t) = w3;
}

// ---------------------------------------------------------------------------
extern "C" void kernel_launch(void* const* d_in, const int* in_sizes, int n_in,
                              void* d_out, int out_size, void* d_ws, size_t ws_size,
                              hipStream_t stream)
{
    const float* z1   = (const float*)d_in[0];
    const float* z2   = (const float*)d_in[1];
    const float* z3   = (const float*)d_in[2];
    const float* mem2 = (const float*)d_in[3];
    const float* mem3 = (const float*)d_in[4];
    const int*   y    = (const int*)d_in[5];
    const int*   idx  = (const int*)d_in[6];
    float*       out  = (float*)d_out;
    float*       ws   = (float*)d_ws;

    // zero Z buckets (512 B) + tile counters (3128 B); z1t starts at byte 4096
    hipMemsetAsync(d_ws, 0, 4096, stream);

    // 1: bucket (b,k) by j-tile + transpose z1
    dim3 gc(18, BB);
    count_prep_kernel<<<gc, 256, 0, stream>>>(z1, y, idx, ws);

    // 2: tiled dense scores + fused copy + scatter exp via inverted index
    gemm_kernel<<<NT, 256, 0, stream>>>(mem2, mem3, ws, out);

    // 3: scale scores by Z + scatter updated rows (block zones)
    finalize_kernel<<<NSCALE_BLK + BB, 256, 0, stream>>>(
        z2, z3, mem2, mem3, y, out, ws);
}